// Round 6
// baseline (1774.909 us; speedup 1.0000x reference)
//
#include <hip/hip_runtime.h>
#include <cmath>

#define D 64
#define KTOT 1024
#define MARGIN_P 0.03125f  // packed-argmax flag margin: trunc err (<=0.0156) + bf16-split err
#define WLCAP 32768        // refine worklist capacity (expected ~4k flagged)

typedef __attribute__((ext_vector_type(8))) short short8;   // 8 bf16 = 4 VGPRs (MFMA A/B frag)
typedef __attribute__((ext_vector_type(4))) float f32x4;    // MFMA C/D frag

__device__ __forceinline__ unsigned short bf16_rne(float f) {
    unsigned u = __float_as_uint(f);
    return (unsigned short)((u + 0x7FFFu + ((u >> 16) & 1u)) >> 16);
}
__device__ __forceinline__ float bf16_hi_as_f32(float f, unsigned short* hbits) {
    unsigned u = __float_as_uint(f);
    unsigned uh = (u + 0x7FFFu + ((u >> 16) & 1u)) & 0xFFFF0000u;
    *hbits = (unsigned short)(uh >> 16);
    return __uint_as_float(uh);
}

// ---------------- K0: pack w into MFMA B-frag layout (hi/lo bf16) + transpose ----------------
__global__ void k_prep_w(const float* __restrict__ w, unsigned short* __restrict__ wpack_hi,
                         unsigned short* __restrict__ wpack_lo, float* __restrict__ wT, int K)
{
    int i = blockIdx.x * blockDim.x + threadIdx.x;   // i = d*K + k
    if (i >= D * K) return;
    int d = i / K, k = i % K;
    float f = w[i];
    unsigned short hb;
    float fh = bf16_hi_as_f32(f, &hb);
    unsigned short lb = bf16_rne(f - fh);
    int t = k >> 4, n = k & 15;
    int kc = d >> 5, q = (d >> 3) & 3, j = d & 7;
    size_t fi = ((size_t)((t * 2 + kc) * 64 + q * 16 + n)) * 8 + j;
    wpack_hi[fi] = hb;
    wpack_lo[fi] = lb;
    wT[(size_t)k * D + d] = f;
}

// ---------------- K1: wn[k] = 0.5*||w_k||^2 (fp64 accum) ----------------
__global__ void k_wn(const float* __restrict__ w, float* __restrict__ wn, int K) {
    int k = blockIdx.x * blockDim.x + threadIdx.x;
    if (k >= K) return;
    double s = 0.0;
    for (int d = 0; d < D; ++d) {
        double v = (double)w[(size_t)d * K + k];
        s += v * v;
    }
    wn[k] = (float)(0.5 * s);
}

// ---------------- K2: MFMA assign, packed-uint argmax + worklist ----------------
__global__ __launch_bounds__(256, 4) void k_assign(
    const float* __restrict__ x, const unsigned short* __restrict__ wpack_hi,
    const unsigned short* __restrict__ wpack_lo, const float* __restrict__ wn,
    unsigned int* __restrict__ idx_out, int* __restrict__ wl, int* __restrict__ wl_count,
    int N, int K)
{
    __shared__ __align__(16) unsigned short lds_hi[8192];  // 16 KB
    __shared__ __align__(16) unsigned short lds_lo[8192];  // 16 KB
    __shared__ float lds_wn[128];

    const int tid = threadIdx.x;
    const int wv = tid >> 6, lane = tid & 63;
    const int col = lane & 15, quad = lane >> 4;
    const long long n0 = (long long)blockIdx.x * 128 + wv * 32;

    short8 a_hi[2][2], a_lo[2][2];
    #pragma unroll
    for (int mt = 0; mt < 2; ++mt) {
        long long row = n0 + mt * 16 + col;
        if (row >= N) row = N - 1;
        const float* xr = x + row * D;
        #pragma unroll
        for (int kc = 0; kc < 2; ++kc) {
            const int dbase = kc * 32 + quad * 8;
            float4 f0 = *(const float4*)(xr + dbase);
            float4 f1 = *(const float4*)(xr + dbase + 4);
            float xs[8] = {f0.x, f0.y, f0.z, f0.w, f1.x, f1.y, f1.z, f1.w};
            short8 h, l;
            #pragma unroll
            for (int j = 0; j < 8; ++j) {
                unsigned short hb;
                float fh = bf16_hi_as_f32(xs[j], &hb);
                h[j] = (short)hb;
                l[j] = (short)bf16_rne(xs[j] - fh);
            }
            a_hi[mt][kc] = h;
            a_lo[mt][kc] = l;
        }
    }

    // packed (biased-value | 1023-code): max_u32 argmax, min/max top-2
    unsigned best[8], sec[8];
    #pragma unroll
    for (int s = 0; s < 8; ++s) { best[s] = 0u; sec[s] = 0u; }

    const int nchunks = K / 128;
    for (int c = 0; c < nchunks; ++c) {
        __syncthreads();
        {
            const uint4* gh = (const uint4*)(wpack_hi + (size_t)c * 8192);
            const uint4* gl = (const uint4*)(wpack_lo + (size_t)c * 8192);
            uint4* lh = (uint4*)lds_hi;
            uint4* ll = (uint4*)lds_lo;
            #pragma unroll
            for (int i = 0; i < 4; ++i) {
                lh[tid + 256 * i] = gh[tid + 256 * i];
                ll[tid + 256 * i] = gl[tid + 256 * i];
            }
            if (tid < 128) lds_wn[tid] = wn[c * 128 + tid];
        }
        __syncthreads();

        #pragma unroll
        for (int tl = 0; tl < 8; ++tl) {
            const int fb = (tl * 2) * 512 + (quad * 16 + col) * 8;
            short8 bh0 = *(const short8*)(lds_hi + fb);
            short8 bl0 = *(const short8*)(lds_lo + fb);
            short8 bh1 = *(const short8*)(lds_hi + fb + 512);
            short8 bl1 = *(const short8*)(lds_lo + fb + 512);
            const float base = 128.0f - lds_wn[tl * 16 + col];   // bias+(-wn) folded into acc init
            const unsigned codebits = 1023u - (unsigned)((c * 8 + tl) * 16 + col);
            #pragma unroll
            for (int mt = 0; mt < 2; ++mt) {
                f32x4 acc = {base, base, base, base};
                acc = __builtin_amdgcn_mfma_f32_16x16x32_bf16(a_hi[mt][0], bh0, acc, 0, 0, 0);
                acc = __builtin_amdgcn_mfma_f32_16x16x32_bf16(a_hi[mt][1], bh1, acc, 0, 0, 0);
                acc = __builtin_amdgcn_mfma_f32_16x16x32_bf16(a_lo[mt][0], bh0, acc, 0, 0, 0);
                acc = __builtin_amdgcn_mfma_f32_16x16x32_bf16(a_lo[mt][1], bh1, acc, 0, 0, 0);
                acc = __builtin_amdgcn_mfma_f32_16x16x32_bf16(a_hi[mt][0], bl0, acc, 0, 0, 0);
                acc = __builtin_amdgcn_mfma_f32_16x16x32_bf16(a_hi[mt][1], bl1, acc, 0, 0, 0);
                #pragma unroll
                for (int r = 0; r < 4; ++r) {
                    unsigned pv = (__float_as_uint(acc[r]) & 0xFFFFFC00u) | codebits;
                    int s = mt * 4 + r;
                    unsigned b = best[s];
                    unsigned mn = pv < b ? pv : b;
                    best[s] = pv > b ? pv : b;
                    sec[s]  = mn > sec[s] ? mn : sec[s];
                }
            }
        }
    }

    // top-2 merge across the 16 columns
    #pragma unroll
    for (int m = 1; m < 16; m <<= 1) {
        #pragma unroll
        for (int s = 0; s < 8; ++s) {
            unsigned ob = __shfl_xor(best[s], m);
            unsigned os = __shfl_xor(sec[s], m);
            unsigned mn = ob < best[s] ? ob : best[s];
            best[s] = ob > best[s] ? ob : best[s];
            sec[s]  = os > sec[s] ? os : sec[s];
            sec[s]  = mn > sec[s] ? mn : sec[s];
        }
    }

    if (col == 0) {
        #pragma unroll
        for (int s = 0; s < 8; ++s) {
            int mt = s >> 2, r = s & 3;
            long long np = n0 + mt * 16 + quad * 4 + r;   // C row = quad*4 + reg
            if (np < N) {
                unsigned code = 1023u - (best[s] & 0x3FFu);
                float vb = __uint_as_float(best[s] & 0xFFFFFC00u);
                float vs = __uint_as_float(sec[s] & 0xFFFFFC00u);
                if ((vb - vs) < MARGIN_P) {
                    idx_out[np] = code | 0x80000000u;
                    int pos = atomicAdd(wl_count, 1);
                    if (pos < WLCAP) wl[pos] = (int)np;
                } else {
                    idx_out[np] = code;
                }
            }
        }
    }
}

// ---------------- K3: fp64 exact rescan of worklist points ----------------
__global__ void k_refine(const float* __restrict__ x, const float* __restrict__ w,
                         unsigned int* __restrict__ idx_io, const int* __restrict__ wl,
                         const int* __restrict__ wl_count, int N, int K)
{
    const int gtid = blockIdx.x * blockDim.x + threadIdx.x;
    const int lane = threadIdx.x & 63;
    const int wave = gtid >> 6;
    const int nwaves = (gridDim.x * blockDim.x) >> 6;
    int nw = wl_count[0];
    if (nw > WLCAP) nw = WLCAP;

    for (int i = wave; i < nw; i += nwaves) {
        long long p = wl[i];
        const float* __restrict__ xp = x + p * D;   // wave-uniform broadcast, L1-hot
        double bt = -1e300;
        int bk = 0;
        for (int k = lane; k < K; k += 64) {        // ascending k/lane; strict > = first-occurrence
            double t = 0.0, s = 0.0;
            #pragma unroll 8
            for (int d = 0; d < D; ++d) {
                double wd = (double)w[(size_t)d * K + k];
                t = fma((double)xp[d], wd, t);
                s = fma(wd, wd, s);
            }
            t -= 0.5 * s;
            if (t > bt) { bt = t; bk = k; }
        }
        #pragma unroll
        for (int off = 32; off > 0; off >>= 1) {
            double ot = __shfl_down(bt, off);
            int    ok = __shfl_down(bk, off);
            if (ot > bt || (ot == bt && ok < bk)) { bt = ot; bk = ok; }
        }
        int fk = __shfl(bk, 0);
        if (lane == 0) idx_io[p] = (unsigned)fk;    // clear flag
    }
}

// ---------------- K4: histogram (LDS-aggregated) ----------------
__global__ void k_hist(const unsigned int* __restrict__ idx, int* __restrict__ counts, int N)
{
    __shared__ int h[KTOT];
    const int tid = threadIdx.x;
    for (int i = tid; i < KTOT; i += blockDim.x) h[i] = 0;
    __syncthreads();
    const int stride = gridDim.x * blockDim.x;
    for (int p = blockIdx.x * blockDim.x + tid; p < N; p += stride)
        atomicAdd(&h[idx[p] & 0x7fffffffu], 1);
    __syncthreads();
    for (int i = tid; i < KTOT; i += blockDim.x)
        if (h[i]) atomicAdd(&counts[i], h[i]);
}

// ---------------- K5: exclusive prefix scan over K=1024 (single block) ----------------
__global__ void k_scan(const int* __restrict__ counts, int* __restrict__ offsets,
                       int* __restrict__ cursor)
{
    __shared__ int a[KTOT];
    const int tid = threadIdx.x;
    int c = counts[tid];
    a[tid] = c;
    __syncthreads();
    for (int off = 1; off < KTOT; off <<= 1) {
        int v = (tid >= off) ? a[tid - off] : 0;
        __syncthreads();
        a[tid] += v;
        __syncthreads();
    }
    int excl = a[tid] - c;
    offsets[tid] = excl;
    cursor[tid] = excl;
}

// ---------------- K6: place point ids into code-sorted order ----------------
__global__ void k_place(const unsigned int* __restrict__ idx, int* __restrict__ cursor,
                        int* __restrict__ order, int N)
{
    const int stride = gridDim.x * blockDim.x;
    for (int p = blockIdx.x * blockDim.x + threadIdx.x; p < N; p += stride) {
        unsigned k = idx[p] & 0x7fffffffu;
        int pos = atomicAdd(&cursor[k], 1);
        order[pos] = p;
    }
}

// ---------------- K7: quantized gather (wave per point) ----------------
__global__ void k_quant(const float* __restrict__ wT, const unsigned int* __restrict__ idx,
                        float* __restrict__ quant, int N)
{
    const int gtid = blockIdx.x * blockDim.x + threadIdx.x;
    const int lane = threadIdx.x & 63;
    const int wave = gtid >> 6;
    const int nwaves = (gridDim.x * blockDim.x) >> 6;
    for (int p = wave; p < N; p += nwaves) {
        unsigned k = idx[p] & 0x7fffffffu;
        quant[(size_t)p * D + lane] = wT[(size_t)k * D + lane];
    }
}

// ---------------- K8: block-per-code segment sum + EMA combine (no atomics) ----------------
__global__ void k_sum(const float* __restrict__ x, const int* __restrict__ order,
                      const int* __restrict__ counts, const int* __restrict__ offsets,
                      const float* __restrict__ c_sum, const float* __restrict__ c_n,
                      float* __restrict__ outw, int K)
{
    __shared__ float red[4][D];
    const int k = blockIdx.x;
    const int tid = threadIdx.x;
    const int wv = tid >> 6, lane = tid & 63;
    const int cnt = counts[k];
    const int off = offsets[k];

    float acc = 0.f;
    for (int i = off + wv; i < off + cnt; i += 4) {
        int p = order[i];                          // wave-uniform
        acc += x[(size_t)p * D + lane];            // coalesced 256B row
    }
    red[wv][lane] = acc;
    __syncthreads();
    if (tid < D) {
        float s = red[0][tid] + red[1][tid] + red[2][tid] + red[3][tid];
        const float g  = 0.99f;
        const float og = (float)(1.0 - 0.99);
        float ns = c_sum[(size_t)tid * K + k] * g + s * og;
        float nn = c_n[k] * g + (float)cnt * og;
        outw[(size_t)tid * K + k] = ns / nn;
    }
}

extern "C" void kernel_launch(void* const* d_in, const int* in_sizes, int n_in,
                              void* d_out, int out_size, void* d_ws, size_t ws_size,
                              hipStream_t stream)
{
    const float* x     = (const float*)d_in[0];
    const float* w     = (const float*)d_in[1];
    const float* c_sum = (const float*)d_in[2];
    const float* c_n   = (const float*)d_in[3];
    const int N = in_sizes[0] / D;
    const int K = in_sizes[3];

    float* quant = (float*)d_out;                      // N*D
    float* outw  = (float*)d_out + (size_t)N * D;      // D*K

    // ws layout: [counts K][wl_count 1][offsets K][cursor K][wl WLCAP][order N][idx N]
    //            [wn K][wT K*D][wpack_hi K*D (ushort)][wpack_lo K*D (ushort)]
    char* ws = (char*)d_ws;
    int* counts   = (int*)ws;
    int* wl_count = counts + K;
    int* offsets  = wl_count + 1;
    int* cursor   = offsets + K;
    int* wl       = cursor + K;
    int* order    = wl + WLCAP;
    unsigned* idx = (unsigned*)(order + N);
    float* wn     = (float*)(idx + N);
    float* wT     = wn + K;
    unsigned short* wpack_hi = (unsigned short*)(wT + (size_t)K * D);
    unsigned short* wpack_lo = wpack_hi + (size_t)K * D;

    hipMemsetAsync(counts, 0, (size_t)(K + 1) * sizeof(int), stream);   // counts + wl_count
    k_prep_w<<<(D * K + 255) / 256, 256, 0, stream>>>(w, wpack_hi, wpack_lo, wT, K);
    k_wn<<<(K + 255) / 256, 256, 0, stream>>>(w, wn, K);

    k_assign<<<(N + 127) / 128, 256, 0, stream>>>(x, wpack_hi, wpack_lo, wn, idx, wl, wl_count, N, K);
    k_refine<<<1024, 256, 0, stream>>>(x, w, idx, wl, wl_count, N, K);

    k_hist<<<256, 256, 0, stream>>>(idx, counts, N);
    k_scan<<<1, KTOT, 0, stream>>>(counts, offsets, cursor);
    k_place<<<512, 256, 0, stream>>>(idx, cursor, order, N);
    k_quant<<<1024, 256, 0, stream>>>(wT, idx, quant, N);
    k_sum<<<K, 256, 0, stream>>>(x, order, counts, offsets, c_sum, c_n, outw, K);
}

// Round 7
// 461.622 us; speedup vs baseline: 3.8449x; 3.8449x over previous
//
#include <hip/hip_runtime.h>
#include <cmath>

#define D 64
#define KTOT 1024
#define MARGIN_P 0.03125f  // packed-argmax flag margin: trunc err (<=0.0156) + bf16-split err
#define WLCAP 32768        // refine worklist capacity (expected ~1-4k flagged)
#define PMASK 0x3FFFFu     // low 18 bits: point id (N = 2^18)

typedef __attribute__((ext_vector_type(8))) short short8;   // 8 bf16 = 4 VGPRs (MFMA A/B frag)
typedef __attribute__((ext_vector_type(4))) float f32x4;    // MFMA C/D frag

__device__ __forceinline__ unsigned short bf16_rne(float f) {
    unsigned u = __float_as_uint(f);
    return (unsigned short)((u + 0x7FFFu + ((u >> 16) & 1u)) >> 16);
}
__device__ __forceinline__ float bf16_hi_as_f32(float f, unsigned short* hbits) {
    unsigned u = __float_as_uint(f);
    unsigned uh = (u + 0x7FFFu + ((u >> 16) & 1u)) & 0xFFFF0000u;
    *hbits = (unsigned short)(uh >> 16);
    return __uint_as_float(uh);
}

// ---------------- K0: pack w into MFMA B-frag layout (hi/lo bf16) + transpose ----------------
__global__ void k_prep_w(const float* __restrict__ w, unsigned short* __restrict__ wpack_hi,
                         unsigned short* __restrict__ wpack_lo, float* __restrict__ wT, int K)
{
    int i = blockIdx.x * blockDim.x + threadIdx.x;   // i = d*K + k
    if (i >= D * K) return;
    int d = i / K, k = i % K;
    float f = w[i];
    unsigned short hb;
    float fh = bf16_hi_as_f32(f, &hb);
    unsigned short lb = bf16_rne(f - fh);
    int t = k >> 4, n = k & 15;
    int kc = d >> 5, q = (d >> 3) & 3, j = d & 7;
    size_t fi = ((size_t)((t * 2 + kc) * 64 + q * 16 + n)) * 8 + j;
    wpack_hi[fi] = hb;
    wpack_lo[fi] = lb;
    wT[(size_t)k * D + d] = f;
}

// ---------------- K1: wn[k] = 0.5*||w_k||^2 (fp64 accum) ----------------
__global__ void k_wn(const float* __restrict__ w, float* __restrict__ wn, int K) {
    int k = blockIdx.x * blockDim.x + threadIdx.x;
    if (k >= K) return;
    double s = 0.0;
    for (int d = 0; d < D; ++d) {
        double v = (double)w[(size_t)d * K + k];
        s += v * v;
    }
    wn[k] = (float)(0.5 * s);
}

// ---------------- K2: MFMA assign, packed-uint argmax + worklist ----------------
__global__ __launch_bounds__(256, 4) void k_assign(
    const float* __restrict__ x, const unsigned short* __restrict__ wpack_hi,
    const unsigned short* __restrict__ wpack_lo, const float* __restrict__ wn,
    unsigned int* __restrict__ idx_out, int* __restrict__ wl, int* __restrict__ wl_count,
    int N, int K)
{
    __shared__ __align__(16) unsigned short lds_hi[8192];  // 16 KB
    __shared__ __align__(16) unsigned short lds_lo[8192];  // 16 KB
    __shared__ float lds_wn[128];

    const int tid = threadIdx.x;
    const int wv = tid >> 6, lane = tid & 63;
    const int col = lane & 15, quad = lane >> 4;
    const long long n0 = (long long)blockIdx.x * 128 + wv * 32;

    short8 a_hi[2][2], a_lo[2][2];
    #pragma unroll
    for (int mt = 0; mt < 2; ++mt) {
        long long row = n0 + mt * 16 + col;
        if (row >= N) row = N - 1;
        const float* xr = x + row * D;
        #pragma unroll
        for (int kc = 0; kc < 2; ++kc) {
            const int dbase = kc * 32 + quad * 8;
            float4 f0 = *(const float4*)(xr + dbase);
            float4 f1 = *(const float4*)(xr + dbase + 4);
            float xs[8] = {f0.x, f0.y, f0.z, f0.w, f1.x, f1.y, f1.z, f1.w};
            short8 h, l;
            #pragma unroll
            for (int j = 0; j < 8; ++j) {
                unsigned short hb;
                float fh = bf16_hi_as_f32(xs[j], &hb);
                h[j] = (short)hb;
                l[j] = (short)bf16_rne(xs[j] - fh);
            }
            a_hi[mt][kc] = h;
            a_lo[mt][kc] = l;
        }
    }

    // packed (biased-value | 1023-code): max_u32 argmax, min/max top-2
    unsigned best[8], sec[8];
    #pragma unroll
    for (int s = 0; s < 8; ++s) { best[s] = 0u; sec[s] = 0u; }

    const int nchunks = K / 128;
    for (int c = 0; c < nchunks; ++c) {
        __syncthreads();
        {
            const uint4* gh = (const uint4*)(wpack_hi + (size_t)c * 8192);
            const uint4* gl = (const uint4*)(wpack_lo + (size_t)c * 8192);
            uint4* lh = (uint4*)lds_hi;
            uint4* ll = (uint4*)lds_lo;
            #pragma unroll
            for (int i = 0; i < 4; ++i) {
                lh[tid + 256 * i] = gh[tid + 256 * i];
                ll[tid + 256 * i] = gl[tid + 256 * i];
            }
            if (tid < 128) lds_wn[tid] = wn[c * 128 + tid];
        }
        __syncthreads();

        #pragma unroll
        for (int tl = 0; tl < 8; ++tl) {
            const int fb = (tl * 2) * 512 + (quad * 16 + col) * 8;
            short8 bh0 = *(const short8*)(lds_hi + fb);
            short8 bl0 = *(const short8*)(lds_lo + fb);
            short8 bh1 = *(const short8*)(lds_hi + fb + 512);
            short8 bl1 = *(const short8*)(lds_lo + fb + 512);
            const float base = 128.0f - lds_wn[tl * 16 + col];   // bias+(-wn) folded into acc init
            const unsigned codebits = 1023u - (unsigned)((c * 8 + tl) * 16 + col);
            #pragma unroll
            for (int mt = 0; mt < 2; ++mt) {
                f32x4 acc = {base, base, base, base};
                acc = __builtin_amdgcn_mfma_f32_16x16x32_bf16(a_hi[mt][0], bh0, acc, 0, 0, 0);
                acc = __builtin_amdgcn_mfma_f32_16x16x32_bf16(a_hi[mt][1], bh1, acc, 0, 0, 0);
                acc = __builtin_amdgcn_mfma_f32_16x16x32_bf16(a_lo[mt][0], bh0, acc, 0, 0, 0);
                acc = __builtin_amdgcn_mfma_f32_16x16x32_bf16(a_lo[mt][1], bh1, acc, 0, 0, 0);
                acc = __builtin_amdgcn_mfma_f32_16x16x32_bf16(a_hi[mt][0], bl0, acc, 0, 0, 0);
                acc = __builtin_amdgcn_mfma_f32_16x16x32_bf16(a_hi[mt][1], bl1, acc, 0, 0, 0);
                #pragma unroll
                for (int r = 0; r < 4; ++r) {
                    unsigned pv = (__float_as_uint(acc[r]) & 0xFFFFFC00u) | codebits;  // v_and_or_b32
                    int s = mt * 4 + r;
                    unsigned b = best[s];
                    unsigned mn = pv < b ? pv : b;
                    best[s] = pv > b ? pv : b;
                    sec[s]  = mn > sec[s] ? mn : sec[s];
                }
            }
        }
    }

    // top-2 merge across the 16 columns
    #pragma unroll
    for (int m = 1; m < 16; m <<= 1) {
        #pragma unroll
        for (int s = 0; s < 8; ++s) {
            unsigned ob = __shfl_xor(best[s], m);
            unsigned os = __shfl_xor(sec[s], m);
            unsigned mn = ob < best[s] ? ob : best[s];
            best[s] = ob > best[s] ? ob : best[s];
            sec[s]  = os > sec[s] ? os : sec[s];
            sec[s]  = mn > sec[s] ? mn : sec[s];
        }
    }

    if (col == 0) {
        #pragma unroll
        for (int s = 0; s < 8; ++s) {
            int mt = s >> 2, r = s & 3;
            long long np = n0 + mt * 16 + quad * 4 + r;   // C row = quad*4 + reg
            if (np < N) {
                unsigned code = 1023u - (best[s] & 0x3FFu);
                float vb = __uint_as_float(best[s] & 0xFFFFFC00u);
                float vs = __uint_as_float(sec[s] & 0xFFFFFC00u);
                if ((vb - vs) < MARGIN_P) {
                    idx_out[np] = code | 0x80000000u;
                    int pos = atomicAdd(wl_count, 1);
                    if (pos < WLCAP) wl[pos] = (int)np;
                } else {
                    idx_out[np] = code;
                }
            }
        }
    }
}

// ---------------- K3: fp64 exact rescan of worklist points ----------------
__global__ void k_refine(const float* __restrict__ x, const float* __restrict__ w,
                         unsigned int* __restrict__ idx_io, const int* __restrict__ wl,
                         const int* __restrict__ wl_count, int N, int K)
{
    const int gtid = blockIdx.x * blockDim.x + threadIdx.x;
    const int lane = threadIdx.x & 63;
    const int wave = gtid >> 6;
    const int nwaves = (gridDim.x * blockDim.x) >> 6;
    int nw = wl_count[0];
    if (nw > WLCAP) nw = WLCAP;

    for (int i = wave; i < nw; i += nwaves) {
        long long p = wl[i];
        const float* __restrict__ xp = x + p * D;   // wave-uniform broadcast, L1-hot
        double bt = -1e300;
        int bk = 0;
        for (int k = lane; k < K; k += 64) {        // ascending k/lane; strict > = first-occurrence
            double t = 0.0, s = 0.0;
            #pragma unroll 8
            for (int d = 0; d < D; ++d) {
                double wd = (double)w[(size_t)d * K + k];
                t = fma((double)xp[d], wd, t);
                s = fma(wd, wd, s);
            }
            t -= 0.5 * s;
            if (t > bt) { bt = t; bk = k; }
        }
        #pragma unroll
        for (int off = 32; off > 0; off >>= 1) {
            double ot = __shfl_down(bt, off);
            int    ok = __shfl_down(bk, off);
            if (ot > bt || (ot == bt && ok < bk)) { bt = ot; bk = ok; }
        }
        int fk = __shfl(bk, 0);
        if (lane == 0) idx_io[p] = (unsigned)fk;    // clear flag
    }
}

// ---------------- K4: histogram (LDS-aggregated) ----------------
__global__ void k_hist(const unsigned int* __restrict__ idx, int* __restrict__ counts, int N)
{
    __shared__ int h[KTOT];
    const int tid = threadIdx.x;
    for (int i = tid; i < KTOT; i += blockDim.x) h[i] = 0;
    __syncthreads();
    const int stride = gridDim.x * blockDim.x;
    for (int p = blockIdx.x * blockDim.x + tid; p < N; p += stride)
        atomicAdd(&h[idx[p] & 0x7fffffffu], 1);
    __syncthreads();
    for (int i = tid; i < KTOT; i += blockDim.x)
        if (h[i]) atomicAdd(&counts[i], h[i]);
}

// ---------------- K5: exclusive prefix scan over K=1024 (single block) ----------------
__global__ void k_scan(const int* __restrict__ counts, int* __restrict__ cursor)
{
    __shared__ int a[KTOT];
    const int tid = threadIdx.x;
    int c = counts[tid];
    a[tid] = c;
    __syncthreads();
    for (int off = 1; off < KTOT; off <<= 1) {
        int v = (tid >= off) ? a[tid - off] : 0;
        __syncthreads();
        a[tid] += v;
        __syncthreads();
    }
    cursor[tid] = a[tid] - c;
}

// ---------------- K6: place packed (code<<18 | point) into code-sorted order ----------------
__global__ void k_place(const unsigned int* __restrict__ idx, int* __restrict__ cursor,
                        unsigned* __restrict__ order, int N)
{
    const int stride = gridDim.x * blockDim.x;
    for (int p = blockIdx.x * blockDim.x + threadIdx.x; p < N; p += stride) {
        unsigned k = idx[p] & 0x7fffffffu;
        int pos = atomicAdd(&cursor[k], 1);
        order[pos] = (k << 18) | (unsigned)p;
    }
}

// ---------------- K7: balanced run-length segment sum + fused quant gather ----------------
// Chunk-per-wave over code-sorted order[] (R6's block-per-code k_sum straggled on
// skewed code popularity: max-count code ran for ~ms). Runs are accumulated in
// registers; one 256B atomic burst per run boundary (~2/chunk).
__global__ void k_sum(const float* __restrict__ x, const float* __restrict__ wT,
                      const unsigned* __restrict__ order, float* __restrict__ quant,
                      float* __restrict__ cs, int N)
{
    const int gtid = blockIdx.x * blockDim.x + threadIdx.x;
    const int lane = threadIdx.x & 63;
    const int wave = gtid >> 6;
    const int nwaves = (gridDim.x * blockDim.x) >> 6;
    const int nchunks = (N + 63) >> 6;

    for (int c = wave; c < nchunks; c += nwaves) {
        const int base = c << 6;
        const int cnt = min(64, N - base);
        unsigned e = order[base + min(lane, cnt - 1)];   // coalesced 256B

        int curk = -1;
        float acc = 0.f, wrow = 0.f;
        // 1-deep software pipeline: next x row in flight while processing current
        unsigned e0 = __shfl(e, 0);
        int k0 = (int)(e0 >> 18), p0 = (int)(e0 & PMASK);
        float v = x[(size_t)p0 * D + lane];
        for (int i = 0; i < cnt; ++i) {
            int kn = 0, pn = 0;
            float vn = 0.f;
            if (i + 1 < cnt) {                           // wave-uniform branch
                unsigned en = __shfl(e, i + 1);
                kn = (int)(en >> 18);
                pn = (int)(en & PMASK);
                vn = x[(size_t)pn * D + lane];
            }
            if (k0 != curk) {                            // wave-uniform
                if (curk >= 0) unsafeAtomicAdd(&cs[(size_t)curk * D + lane], acc);
                wrow = wT[(size_t)k0 * D + lane];        // L2-hot
                acc = v;
                curk = k0;
            } else {
                acc += v;
            }
            quant[(size_t)p0 * D + lane] = wrow;
            k0 = kn; p0 = pn; v = vn;
        }
        unsafeAtomicAdd(&cs[(size_t)curk * D + lane], acc);
    }
}

// ---------------- K8: EMA combine -> new_w [D][K] ----------------
__global__ void k_combine(const float* __restrict__ c_sum, const float* __restrict__ c_n,
                          const float* __restrict__ cs, const int* __restrict__ counts,
                          float* __restrict__ outw, int K)
{
    int i = blockIdx.x * blockDim.x + threadIdx.x;   // i = d*K + k
    if (i >= D * K) return;
    int k = i % K;
    int d = i / K;
    const float g  = 0.99f;
    const float og = (float)(1.0 - 0.99);
    float ns = c_sum[i] * g + cs[(size_t)k * D + d] * og;
    float nn = c_n[k] * g + (float)counts[k] * og;
    outw[i] = ns / nn;
}

extern "C" void kernel_launch(void* const* d_in, const int* in_sizes, int n_in,
                              void* d_out, int out_size, void* d_ws, size_t ws_size,
                              hipStream_t stream)
{
    const float* x     = (const float*)d_in[0];
    const float* w     = (const float*)d_in[1];
    const float* c_sum = (const float*)d_in[2];
    const float* c_n   = (const float*)d_in[3];
    const int N = in_sizes[0] / D;
    const int K = in_sizes[3];

    float* quant = (float*)d_out;                      // N*D
    float* outw  = (float*)d_out + (size_t)N * D;      // D*K

    // ws layout: [cs K*D][counts K][wl_count 1] (one memset) | [cursor K][wl WLCAP]
    //            [order N][idx N][wn K][wT K*D][wpack_hi][wpack_lo]
    char* ws = (char*)d_ws;
    float* cs     = (float*)ws;                        // K*D
    int* counts   = (int*)(cs + (size_t)K * D);        // K
    int* wl_count = counts + K;                        // 1
    int* cursor   = wl_count + 1;                      // K
    int* wl       = cursor + K;                        // WLCAP
    unsigned* order = (unsigned*)(wl + WLCAP);         // N
    unsigned* idx = order + N;                         // N
    float* wn     = (float*)(idx + N);                 // K
    float* wT     = wn + K;                            // K*D
    unsigned short* wpack_hi = (unsigned short*)(wT + (size_t)K * D);
    unsigned short* wpack_lo = wpack_hi + (size_t)K * D;

    hipMemsetAsync(cs, 0, ((size_t)K * D + K + 1) * sizeof(float), stream);
    k_prep_w<<<(D * K + 255) / 256, 256, 0, stream>>>(w, wpack_hi, wpack_lo, wT, K);
    k_wn<<<(K + 255) / 256, 256, 0, stream>>>(w, wn, K);

    k_assign<<<(N + 127) / 128, 256, 0, stream>>>(x, wpack_hi, wpack_lo, wn, idx, wl, wl_count, N, K);
    k_refine<<<1024, 256, 0, stream>>>(x, w, idx, wl, wl_count, N, K);

    k_hist<<<256, 256, 0, stream>>>(idx, counts, N);
    k_scan<<<1, KTOT, 0, stream>>>(counts, cursor);
    k_place<<<512, 256, 0, stream>>>(idx, cursor, order, N);
    k_sum<<<1024, 256, 0, stream>>>(x, wT, order, quant, cs, N);
    k_combine<<<(D * K + 255) / 256, 256, 0, stream>>>(c_sum, c_n, cs, counts, outw, K);
}

// Round 8
// 451.506 us; speedup vs baseline: 3.9311x; 1.0224x over previous
//
#include <hip/hip_runtime.h>
#include <cmath>

#define D 64
#define KTOT 1024
#define MARGIN_P 0.03125f  // packed-argmax flag margin: trunc err (<=0.0156) + bf16-split err
#define WLCAP 32768        // refine worklist capacity (expected ~1-4k flagged)
#define PMASK 0x3FFFFu     // low 18 bits: point id (N = 2^18)
#define CPAD 64            // pad atomically-hit counters to one per 256B line (R7: 8192 RMW/line = 157us)

typedef __attribute__((ext_vector_type(8))) short short8;   // 8 bf16 = 4 VGPRs (MFMA A/B frag)
typedef __attribute__((ext_vector_type(4))) float f32x4;    // MFMA C/D frag

__device__ __forceinline__ unsigned short bf16_rne(float f) {
    unsigned u = __float_as_uint(f);
    return (unsigned short)((u + 0x7FFFu + ((u >> 16) & 1u)) >> 16);
}
__device__ __forceinline__ float bf16_hi_as_f32(float f, unsigned short* hbits) {
    unsigned u = __float_as_uint(f);
    unsigned uh = (u + 0x7FFFu + ((u >> 16) & 1u)) & 0xFFFF0000u;
    *hbits = (unsigned short)(uh >> 16);
    return __uint_as_float(uh);
}

// ---------------- K0: pack w into MFMA B-frag layout (hi/lo bf16) + transpose ----------------
__global__ void k_prep_w(const float* __restrict__ w, unsigned short* __restrict__ wpack_hi,
                         unsigned short* __restrict__ wpack_lo, float* __restrict__ wT, int K)
{
    int i = blockIdx.x * blockDim.x + threadIdx.x;   // i = d*K + k
    if (i >= D * K) return;
    int d = i / K, k = i % K;
    float f = w[i];
    unsigned short hb;
    float fh = bf16_hi_as_f32(f, &hb);
    unsigned short lb = bf16_rne(f - fh);
    int t = k >> 4, n = k & 15;
    int kc = d >> 5, q = (d >> 3) & 3, j = d & 7;
    size_t fi = ((size_t)((t * 2 + kc) * 64 + q * 16 + n)) * 8 + j;
    wpack_hi[fi] = hb;
    wpack_lo[fi] = lb;
    wT[(size_t)k * D + d] = f;
}

// ---------------- K1: wn[k] = 0.5*||w_k||^2 (fp64 accum) ----------------
__global__ void k_wn(const float* __restrict__ w, float* __restrict__ wn, int K) {
    int k = blockIdx.x * blockDim.x + threadIdx.x;
    if (k >= K) return;
    double s = 0.0;
    for (int d = 0; d < D; ++d) {
        double v = (double)w[(size_t)d * K + k];
        s += v * v;
    }
    wn[k] = (float)(0.5 * s);
}

// ---------------- K2: MFMA assign, packed-uint argmax + block-aggregated worklist ----------------
__global__ __launch_bounds__(256, 4) void k_assign(
    const float* __restrict__ x, const unsigned short* __restrict__ wpack_hi,
    const unsigned short* __restrict__ wpack_lo, const float* __restrict__ wn,
    unsigned int* __restrict__ idx_out, int* __restrict__ wl, int* __restrict__ wl_count,
    int N, int K)
{
    __shared__ __align__(16) unsigned short lds_hi[8192];  // 16 KB
    __shared__ __align__(16) unsigned short lds_lo[8192];  // 16 KB
    __shared__ float lds_wn[128];
    __shared__ int l_wl[128];    // 128 = physical max points/block -> no overflow path
    __shared__ int l_cnt, l_base;

    const int tid = threadIdx.x;
    const int wv = tid >> 6, lane = tid & 63;
    const int col = lane & 15, quad = lane >> 4;
    const long long n0 = (long long)blockIdx.x * 128 + wv * 32;
    if (tid == 0) l_cnt = 0;

    short8 a_hi[2][2], a_lo[2][2];
    #pragma unroll
    for (int mt = 0; mt < 2; ++mt) {
        long long row = n0 + mt * 16 + col;
        if (row >= N) row = N - 1;
        const float* xr = x + row * D;
        #pragma unroll
        for (int kc = 0; kc < 2; ++kc) {
            const int dbase = kc * 32 + quad * 8;
            float4 f0 = *(const float4*)(xr + dbase);
            float4 f1 = *(const float4*)(xr + dbase + 4);
            float xs[8] = {f0.x, f0.y, f0.z, f0.w, f1.x, f1.y, f1.z, f1.w};
            short8 h, l;
            #pragma unroll
            for (int j = 0; j < 8; ++j) {
                unsigned short hb;
                float fh = bf16_hi_as_f32(xs[j], &hb);
                h[j] = (short)hb;
                l[j] = (short)bf16_rne(xs[j] - fh);
            }
            a_hi[mt][kc] = h;
            a_lo[mt][kc] = l;
        }
    }

    // packed (biased-value | 1023-code): max_u32 argmax, min/max top-2
    unsigned best[8], sec[8];
    #pragma unroll
    for (int s = 0; s < 8; ++s) { best[s] = 0u; sec[s] = 0u; }

    const int nchunks = K / 128;
    for (int c = 0; c < nchunks; ++c) {
        __syncthreads();
        {
            const uint4* gh = (const uint4*)(wpack_hi + (size_t)c * 8192);
            const uint4* gl = (const uint4*)(wpack_lo + (size_t)c * 8192);
            uint4* lh = (uint4*)lds_hi;
            uint4* ll = (uint4*)lds_lo;
            #pragma unroll
            for (int i = 0; i < 4; ++i) {
                lh[tid + 256 * i] = gh[tid + 256 * i];
                ll[tid + 256 * i] = gl[tid + 256 * i];
            }
            if (tid < 128) lds_wn[tid] = wn[c * 128 + tid];
        }
        __syncthreads();

        #pragma unroll
        for (int tl = 0; tl < 8; ++tl) {
            const int fb = (tl * 2) * 512 + (quad * 16 + col) * 8;
            short8 bh0 = *(const short8*)(lds_hi + fb);
            short8 bl0 = *(const short8*)(lds_lo + fb);
            short8 bh1 = *(const short8*)(lds_hi + fb + 512);
            short8 bl1 = *(const short8*)(lds_lo + fb + 512);
            const float base = 128.0f - lds_wn[tl * 16 + col];   // bias+(-wn) folded into acc init
            const unsigned codebits = 1023u - (unsigned)((c * 8 + tl) * 16 + col);
            #pragma unroll
            for (int mt = 0; mt < 2; ++mt) {
                f32x4 acc = {base, base, base, base};
                acc = __builtin_amdgcn_mfma_f32_16x16x32_bf16(a_hi[mt][0], bh0, acc, 0, 0, 0);
                acc = __builtin_amdgcn_mfma_f32_16x16x32_bf16(a_hi[mt][1], bh1, acc, 0, 0, 0);
                acc = __builtin_amdgcn_mfma_f32_16x16x32_bf16(a_lo[mt][0], bh0, acc, 0, 0, 0);
                acc = __builtin_amdgcn_mfma_f32_16x16x32_bf16(a_lo[mt][1], bh1, acc, 0, 0, 0);
                acc = __builtin_amdgcn_mfma_f32_16x16x32_bf16(a_hi[mt][0], bl0, acc, 0, 0, 0);
                acc = __builtin_amdgcn_mfma_f32_16x16x32_bf16(a_hi[mt][1], bl1, acc, 0, 0, 0);
                #pragma unroll
                for (int r = 0; r < 4; ++r) {
                    unsigned pv = (__float_as_uint(acc[r]) & 0xFFFFFC00u) | codebits;  // v_and_or_b32
                    int s = mt * 4 + r;
                    unsigned b = best[s];
                    unsigned mn = pv < b ? pv : b;
                    best[s] = pv > b ? pv : b;
                    sec[s]  = mn > sec[s] ? mn : sec[s];
                }
            }
        }
    }

    // top-2 merge across the 16 columns
    #pragma unroll
    for (int m = 1; m < 16; m <<= 1) {
        #pragma unroll
        for (int s = 0; s < 8; ++s) {
            unsigned ob = __shfl_xor(best[s], m);
            unsigned os = __shfl_xor(sec[s], m);
            unsigned mn = ob < best[s] ? ob : best[s];
            best[s] = ob > best[s] ? ob : best[s];
            sec[s]  = os > sec[s] ? os : sec[s];
            sec[s]  = mn > sec[s] ? mn : sec[s];
        }
    }

    if (col == 0) {
        #pragma unroll
        for (int s = 0; s < 8; ++s) {
            int mt = s >> 2, r = s & 3;
            long long np = n0 + mt * 16 + quad * 4 + r;   // C row = quad*4 + reg
            if (np < N) {
                unsigned code = 1023u - (best[s] & 0x3FFu);
                float vb = __uint_as_float(best[s] & 0xFFFFFC00u);
                float vs = __uint_as_float(sec[s] & 0xFFFFFC00u);
                if ((vb - vs) < MARGIN_P) {
                    idx_out[np] = code | 0x80000000u;
                    int q = atomicAdd(&l_cnt, 1);        // LDS atomic (block-local)
                    l_wl[q] = (int)np;
                } else {
                    idx_out[np] = code;
                }
            }
        }
    }
    __syncthreads();
    if (tid == 0 && l_cnt > 0) l_base = atomicAdd(wl_count, l_cnt);  // one global RMW per block
    __syncthreads();
    for (int i = tid; i < l_cnt; i += 256) {
        int pos = l_base + i;
        if (pos < WLCAP) wl[pos] = l_wl[i];
    }
}

// ---------------- K3: fp64 exact rescan of worklist points ----------------
__global__ void k_refine(const float* __restrict__ x, const float* __restrict__ w,
                         unsigned int* __restrict__ idx_io, const int* __restrict__ wl,
                         const int* __restrict__ wl_count, int N, int K)
{
    const int gtid = blockIdx.x * blockDim.x + threadIdx.x;
    const int lane = threadIdx.x & 63;
    const int wave = gtid >> 6;
    const int nwaves = (gridDim.x * blockDim.x) >> 6;
    int nw = wl_count[0];
    if (nw > WLCAP) nw = WLCAP;

    for (int i = wave; i < nw; i += nwaves) {
        long long p = wl[i];
        const float* __restrict__ xp = x + p * D;   // wave-uniform broadcast, L1-hot
        double bt = -1e300;
        int bk = 0;
        for (int k = lane; k < K; k += 64) {        // ascending k/lane; strict > = first-occurrence
            double t = 0.0, s = 0.0;
            #pragma unroll 8
            for (int d = 0; d < D; ++d) {
                double wd = (double)w[(size_t)d * K + k];
                t = fma((double)xp[d], wd, t);
                s = fma(wd, wd, s);
            }
            t -= 0.5 * s;
            if (t > bt) { bt = t; bk = k; }
        }
        #pragma unroll
        for (int off = 32; off > 0; off >>= 1) {
            double ot = __shfl_down(bt, off);
            int    ok = __shfl_down(bk, off);
            if (ot > bt || (ot == bt && ok < bk)) { bt = ot; bk = ok; }
        }
        int fk = __shfl(bk, 0);
        if (lane == 0) idx_io[p] = (unsigned)fk;    // clear flag
    }
}

// ---------------- K4: histogram (LDS-aggregated, line-padded flush) ----------------
__global__ void k_hist(const unsigned int* __restrict__ idx, int* __restrict__ counts_pad, int N)
{
    __shared__ int h[KTOT];
    const int tid = threadIdx.x;
    for (int i = tid; i < KTOT; i += blockDim.x) h[i] = 0;
    __syncthreads();
    const int stride = gridDim.x * blockDim.x;
    for (int p = blockIdx.x * blockDim.x + tid; p < N; p += stride)
        atomicAdd(&h[idx[p] & 0x7fffffffu], 1);
    __syncthreads();
    for (int i = tid; i < KTOT; i += blockDim.x)
        if (h[i]) atomicAdd(&counts_pad[i * CPAD], h[i]);
}

// ---------------- K5: exclusive prefix scan over K=1024 (single block) ----------------
__global__ void k_scan(const int* __restrict__ counts_pad, int* __restrict__ cursor_pad,
                       int* __restrict__ counts)
{
    __shared__ int a[KTOT];
    const int tid = threadIdx.x;
    int c = counts_pad[tid * CPAD];
    a[tid] = c;
    __syncthreads();
    for (int off = 1; off < KTOT; off <<= 1) {
        int v = (tid >= off) ? a[tid - off] : 0;
        __syncthreads();
        a[tid] += v;
        __syncthreads();
    }
    cursor_pad[tid * CPAD] = a[tid] - c;
    counts[tid] = c;                      // compact copy for k_combine
}

// ---------------- K6: place packed (code<<18 | point) into code-sorted order ----------------
__global__ void k_place(const unsigned int* __restrict__ idx, int* __restrict__ cursor_pad,
                        unsigned* __restrict__ order, int N)
{
    const int stride = gridDim.x * blockDim.x;
    for (int p = blockIdx.x * blockDim.x + threadIdx.x; p < N; p += stride) {
        unsigned k = idx[p] & 0x7fffffffu;
        int pos = atomicAdd(&cursor_pad[k * CPAD], 1);   // own 256B line per code
        order[pos] = (k << 18) | (unsigned)p;
    }
}

// ---------------- K7: balanced run-length segment sum + fused quant gather ----------------
__global__ void k_sum(const float* __restrict__ x, const float* __restrict__ wT,
                      const unsigned* __restrict__ order, float* __restrict__ quant,
                      float* __restrict__ cs, int N)
{
    const int gtid = blockIdx.x * blockDim.x + threadIdx.x;
    const int lane = threadIdx.x & 63;
    const int wave = gtid >> 6;
    const int nwaves = (gridDim.x * blockDim.x) >> 6;
    const int nchunks = (N + 63) >> 6;

    for (int c = wave; c < nchunks; c += nwaves) {
        const int base = c << 6;
        const int cnt = min(64, N - base);
        unsigned e = order[base + min(lane, cnt - 1)];   // coalesced 256B

        int curk = -1;
        float acc = 0.f, wrow = 0.f;
        unsigned e0 = __shfl(e, 0);
        int k0 = (int)(e0 >> 18), p0 = (int)(e0 & PMASK);
        float v = x[(size_t)p0 * D + lane];
        for (int i = 0; i < cnt; ++i) {
            int kn = 0, pn = 0;
            float vn = 0.f;
            if (i + 1 < cnt) {                           // wave-uniform branch
                unsigned en = __shfl(e, i + 1);
                kn = (int)(en >> 18);
                pn = (int)(en & PMASK);
                vn = x[(size_t)pn * D + lane];
            }
            if (k0 != curk) {                            // wave-uniform
                if (curk >= 0) unsafeAtomicAdd(&cs[(size_t)curk * D + lane], acc);
                wrow = wT[(size_t)k0 * D + lane];        // L2-hot
                acc = v;
                curk = k0;
            } else {
                acc += v;
            }
            quant[(size_t)p0 * D + lane] = wrow;
            k0 = kn; p0 = pn; v = vn;
        }
        unsafeAtomicAdd(&cs[(size_t)curk * D + lane], acc);
    }
}

// ---------------- K8: EMA combine -> new_w [D][K] ----------------
__global__ void k_combine(const float* __restrict__ c_sum, const float* __restrict__ c_n,
                          const float* __restrict__ cs, const int* __restrict__ counts,
                          float* __restrict__ outw, int K)
{
    int i = blockIdx.x * blockDim.x + threadIdx.x;   // i = d*K + k
    if (i >= D * K) return;
    int k = i % K;
    int d = i / K;
    const float g  = 0.99f;
    const float og = (float)(1.0 - 0.99);
    float ns = c_sum[i] * g + cs[(size_t)k * D + d] * og;
    float nn = c_n[k] * g + (float)counts[k] * og;
    outw[i] = ns / nn;
}

extern "C" void kernel_launch(void* const* d_in, const int* in_sizes, int n_in,
                              void* d_out, int out_size, void* d_ws, size_t ws_size,
                              hipStream_t stream)
{
    const float* x     = (const float*)d_in[0];
    const float* w     = (const float*)d_in[1];
    const float* c_sum = (const float*)d_in[2];
    const float* c_n   = (const float*)d_in[3];
    const int N = in_sizes[0] / D;
    const int K = in_sizes[3];

    float* quant = (float*)d_out;                      // N*D
    float* outw  = (float*)d_out + (size_t)N * D;      // D*K

    // ws layout: [cs K*D][counts_pad K*CPAD][wl_count 1]  <- one memset covers these
    //            [counts K][cursor_pad K*CPAD][wl WLCAP][order N][idx N][wn K][wT K*D][wpacks]
    char* ws = (char*)d_ws;
    float* cs       = (float*)ws;                      // K*D
    int* counts_pad = (int*)(cs + (size_t)K * D);      // K*CPAD
    int* wl_count   = counts_pad + (size_t)K * CPAD;   // 1
    int* counts     = wl_count + 1;                    // K (written fully by k_scan)
    int* cursor_pad = counts + K;                      // K*CPAD (written fully by k_scan)
    int* wl         = cursor_pad + (size_t)K * CPAD;   // WLCAP
    unsigned* order = (unsigned*)(wl + WLCAP);         // N
    unsigned* idx   = order + N;                       // N
    float* wn       = (float*)(idx + N);               // K
    float* wT       = wn + K;                          // K*D
    unsigned short* wpack_hi = (unsigned short*)(wT + (size_t)K * D);
    unsigned short* wpack_lo = wpack_hi + (size_t)K * D;

    hipMemsetAsync(cs, 0, ((size_t)K * D + (size_t)K * CPAD + 1) * sizeof(float), stream);
    k_prep_w<<<(D * K + 255) / 256, 256, 0, stream>>>(w, wpack_hi, wpack_lo, wT, K);
    k_wn<<<(K + 255) / 256, 256, 0, stream>>>(w, wn, K);

    k_assign<<<(N + 127) / 128, 256, 0, stream>>>(x, wpack_hi, wpack_lo, wn, idx, wl, wl_count, N, K);
    k_refine<<<1024, 256, 0, stream>>>(x, w, idx, wl, wl_count, N, K);

    k_hist<<<256, 256, 0, stream>>>(idx, counts_pad, N);
    k_scan<<<1, KTOT, 0, stream>>>(counts_pad, cursor_pad, counts);
    k_place<<<512, 256, 0, stream>>>(idx, cursor_pad, order, N);
    k_sum<<<1024, 256, 0, stream>>>(x, wT, order, quant, cs, N);
    k_combine<<<(D * K + 255) / 256, 256, 0, stream>>>(c_sum, c_n, cs, counts, outw, K);
}

// Round 9
// 313.677 us; speedup vs baseline: 5.6584x; 1.4394x over previous
//
#include <hip/hip_runtime.h>
#include <cmath>

#define D 64
#define KTOT 1024
#define MARGIN_P 0.03125f  // packed-argmax flag margin: trunc err (<=0.0156) + bf16-split err
#define WLCAP 32768        // refine worklist capacity (expected ~1-4k flagged)
#define PMASK 0x3FFFFu     // low 18 bits: point id (N = 2^18)
#define NB 128             // blocks for hist/place counting sort

typedef __attribute__((ext_vector_type(8))) short short8;   // 8 bf16 = 4 VGPRs (MFMA A/B frag)
typedef __attribute__((ext_vector_type(4))) float f32x4;    // MFMA C/D frag

__device__ __forceinline__ unsigned short bf16_rne(float f) {
    unsigned u = __float_as_uint(f);
    return (unsigned short)((u + 0x7FFFu + ((u >> 16) & 1u)) >> 16);
}
__device__ __forceinline__ float bf16_hi_as_f32(float f, unsigned short* hbits) {
    unsigned u = __float_as_uint(f);
    unsigned uh = (u + 0x7FFFu + ((u >> 16) & 1u)) & 0xFFFF0000u;
    *hbits = (unsigned short)(uh >> 16);
    return __uint_as_float(uh);
}

// ---------------- K0: pack w into MFMA B-frag layout (hi/lo bf16) + transpose ----------------
__global__ void k_prep_w(const float* __restrict__ w, unsigned short* __restrict__ wpack_hi,
                         unsigned short* __restrict__ wpack_lo, float* __restrict__ wT, int K)
{
    int i = blockIdx.x * blockDim.x + threadIdx.x;   // i = d*K + k
    if (i >= D * K) return;
    int d = i / K, k = i % K;
    float f = w[i];
    unsigned short hb;
    float fh = bf16_hi_as_f32(f, &hb);
    unsigned short lb = bf16_rne(f - fh);
    int t = k >> 4, n = k & 15;
    int kc = d >> 5, q = (d >> 3) & 3, j = d & 7;
    size_t fi = ((size_t)((t * 2 + kc) * 64 + q * 16 + n)) * 8 + j;
    wpack_hi[fi] = hb;
    wpack_lo[fi] = lb;
    wT[(size_t)k * D + d] = f;
}

// ---------------- K1: wn[k] = 0.5*||w_k||^2 (fp64 accum) ----------------
__global__ void k_wn(const float* __restrict__ w, float* __restrict__ wn, int K) {
    int k = blockIdx.x * blockDim.x + threadIdx.x;
    if (k >= K) return;
    double s = 0.0;
    for (int d = 0; d < D; ++d) {
        double v = (double)w[(size_t)d * K + k];
        s += v * v;
    }
    wn[k] = (float)(0.5 * s);
}

// ---------------- K2: MFMA assign, packed-uint argmax + block-aggregated worklist ----------------
__global__ __launch_bounds__(256, 4) void k_assign(
    const float* __restrict__ x, const unsigned short* __restrict__ wpack_hi,
    const unsigned short* __restrict__ wpack_lo, const float* __restrict__ wn,
    unsigned int* __restrict__ idx_out, int* __restrict__ wl, int* __restrict__ wl_count,
    int N, int K)
{
    __shared__ __align__(16) unsigned short lds_hi[8192];  // 16 KB
    __shared__ __align__(16) unsigned short lds_lo[8192];  // 16 KB
    __shared__ float lds_wn[128];
    __shared__ int l_wl[128];    // 128 = physical max points/block -> no overflow path
    __shared__ int l_cnt, l_base;

    const int tid = threadIdx.x;
    const int wv = tid >> 6, lane = tid & 63;
    const int col = lane & 15, quad = lane >> 4;
    const long long n0 = (long long)blockIdx.x * 128 + wv * 32;
    if (tid == 0) l_cnt = 0;

    short8 a_hi[2][2], a_lo[2][2];
    #pragma unroll
    for (int mt = 0; mt < 2; ++mt) {
        long long row = n0 + mt * 16 + col;
        if (row >= N) row = N - 1;
        const float* xr = x + row * D;
        #pragma unroll
        for (int kc = 0; kc < 2; ++kc) {
            const int dbase = kc * 32 + quad * 8;
            float4 f0 = *(const float4*)(xr + dbase);
            float4 f1 = *(const float4*)(xr + dbase + 4);
            float xs[8] = {f0.x, f0.y, f0.z, f0.w, f1.x, f1.y, f1.z, f1.w};
            short8 h, l;
            #pragma unroll
            for (int j = 0; j < 8; ++j) {
                unsigned short hb;
                float fh = bf16_hi_as_f32(xs[j], &hb);
                h[j] = (short)hb;
                l[j] = (short)bf16_rne(xs[j] - fh);
            }
            a_hi[mt][kc] = h;
            a_lo[mt][kc] = l;
        }
    }

    // packed (biased-value | 1023-code): max_u32 argmax, min/max top-2
    unsigned best[8], sec[8];
    #pragma unroll
    for (int s = 0; s < 8; ++s) { best[s] = 0u; sec[s] = 0u; }

    const int nchunks = K / 128;
    for (int c = 0; c < nchunks; ++c) {
        __syncthreads();
        {
            const uint4* gh = (const uint4*)(wpack_hi + (size_t)c * 8192);
            const uint4* gl = (const uint4*)(wpack_lo + (size_t)c * 8192);
            uint4* lh = (uint4*)lds_hi;
            uint4* ll = (uint4*)lds_lo;
            #pragma unroll
            for (int i = 0; i < 4; ++i) {
                lh[tid + 256 * i] = gh[tid + 256 * i];
                ll[tid + 256 * i] = gl[tid + 256 * i];
            }
            if (tid < 128) lds_wn[tid] = wn[c * 128 + tid];
        }
        __syncthreads();

        #pragma unroll
        for (int tl = 0; tl < 8; ++tl) {
            const int fb = (tl * 2) * 512 + (quad * 16 + col) * 8;
            short8 bh0 = *(const short8*)(lds_hi + fb);
            short8 bl0 = *(const short8*)(lds_lo + fb);
            short8 bh1 = *(const short8*)(lds_hi + fb + 512);
            short8 bl1 = *(const short8*)(lds_lo + fb + 512);
            const float base = 128.0f - lds_wn[tl * 16 + col];   // bias+(-wn) folded into acc init
            const unsigned codebits = 1023u - (unsigned)((c * 8 + tl) * 16 + col);
            #pragma unroll
            for (int mt = 0; mt < 2; ++mt) {
                f32x4 acc = {base, base, base, base};
                acc = __builtin_amdgcn_mfma_f32_16x16x32_bf16(a_hi[mt][0], bh0, acc, 0, 0, 0);
                acc = __builtin_amdgcn_mfma_f32_16x16x32_bf16(a_hi[mt][1], bh1, acc, 0, 0, 0);
                acc = __builtin_amdgcn_mfma_f32_16x16x32_bf16(a_lo[mt][0], bh0, acc, 0, 0, 0);
                acc = __builtin_amdgcn_mfma_f32_16x16x32_bf16(a_lo[mt][1], bh1, acc, 0, 0, 0);
                acc = __builtin_amdgcn_mfma_f32_16x16x32_bf16(a_hi[mt][0], bl0, acc, 0, 0, 0);
                acc = __builtin_amdgcn_mfma_f32_16x16x32_bf16(a_hi[mt][1], bl1, acc, 0, 0, 0);
                #pragma unroll
                for (int r = 0; r < 4; ++r) {
                    unsigned pv = (__float_as_uint(acc[r]) & 0xFFFFFC00u) | codebits;  // v_and_or_b32
                    int s = mt * 4 + r;
                    unsigned b = best[s];
                    unsigned mn = pv < b ? pv : b;
                    best[s] = pv > b ? pv : b;
                    sec[s]  = mn > sec[s] ? mn : sec[s];
                }
            }
        }
    }

    // top-2 merge across the 16 columns
    #pragma unroll
    for (int m = 1; m < 16; m <<= 1) {
        #pragma unroll
        for (int s = 0; s < 8; ++s) {
            unsigned ob = __shfl_xor(best[s], m);
            unsigned os = __shfl_xor(sec[s], m);
            unsigned mn = ob < best[s] ? ob : best[s];
            best[s] = ob > best[s] ? ob : best[s];
            sec[s]  = os > sec[s] ? os : sec[s];
            sec[s]  = mn > sec[s] ? mn : sec[s];
        }
    }

    if (col == 0) {
        #pragma unroll
        for (int s = 0; s < 8; ++s) {
            int mt = s >> 2, r = s & 3;
            long long np = n0 + mt * 16 + quad * 4 + r;   // C row = quad*4 + reg
            if (np < N) {
                unsigned code = 1023u - (best[s] & 0x3FFu);
                float vb = __uint_as_float(best[s] & 0xFFFFFC00u);
                float vs = __uint_as_float(sec[s] & 0xFFFFFC00u);
                if ((vb - vs) < MARGIN_P) {
                    idx_out[np] = code | 0x80000000u;
                    int q = atomicAdd(&l_cnt, 1);        // LDS atomic (block-local)
                    l_wl[q] = (int)np;
                } else {
                    idx_out[np] = code;
                }
            }
        }
    }
    __syncthreads();
    if (tid == 0 && l_cnt > 0) l_base = atomicAdd(wl_count, l_cnt);  // one global RMW per block
    __syncthreads();
    for (int i = tid; i < l_cnt; i += 256) {
        int pos = l_base + i;
        if (pos < WLCAP) wl[pos] = l_wl[i];
    }
}

// ---------------- K3: fp64 exact rescan of worklist points ----------------
__global__ void k_refine(const float* __restrict__ x, const float* __restrict__ w,
                         unsigned int* __restrict__ idx_io, const int* __restrict__ wl,
                         const int* __restrict__ wl_count, int N, int K)
{
    const int gtid = blockIdx.x * blockDim.x + threadIdx.x;
    const int lane = threadIdx.x & 63;
    const int wave = gtid >> 6;
    const int nwaves = (gridDim.x * blockDim.x) >> 6;
    int nw = wl_count[0];
    if (nw > WLCAP) nw = WLCAP;

    for (int i = wave; i < nw; i += nwaves) {
        long long p = wl[i];
        const float* __restrict__ xp = x + p * D;   // wave-uniform broadcast, L1-hot
        double bt = -1e300;
        int bk = 0;
        for (int k = lane; k < K; k += 64) {        // ascending k/lane; strict > = first-occurrence
            double t = 0.0, s = 0.0;
            #pragma unroll 8
            for (int d = 0; d < D; ++d) {
                double wd = (double)w[(size_t)d * K + k];
                t = fma((double)xp[d], wd, t);
                s = fma(wd, wd, s);
            }
            t -= 0.5 * s;
            if (t > bt) { bt = t; bk = k; }
        }
        #pragma unroll
        for (int off = 32; off > 0; off >>= 1) {
            double ot = __shfl_down(bt, off);
            int    ok = __shfl_down(bk, off);
            if (ot > bt || (ot == bt && ok < bk)) { bt = ot; bk = ok; }
        }
        int fk = __shfl(bk, 0);
        if (lane == 0) idx_io[p] = (unsigned)fk;    // clear flag
    }
}

// ---------------- K4: per-block histogram, plain writes (no global atomics) ----------------
__global__ void k_hist2(const unsigned int* __restrict__ idx, int* __restrict__ hist, int N)
{
    __shared__ int h[KTOT];
    const int tid = threadIdx.x;
    const int b = blockIdx.x;
    for (int i = tid; i < KTOT; i += blockDim.x) h[i] = 0;
    __syncthreads();
    const int chunk = N / NB;
    const int p0 = b * chunk;
    for (int i = tid; i < chunk; i += blockDim.x)
        atomicAdd(&h[idx[p0 + i] & 0x7fffffffu], 1);
    __syncthreads();
    for (int i = tid; i < KTOT; i += blockDim.x)
        hist[(size_t)b * KTOT + i] = h[i];
}

// ---------------- K5a: per-code scan over blocks: hist[b][k] -> excl base; counts[k]=total ----------------
__global__ void k_tot(int* __restrict__ hist, int* __restrict__ counts)
{
    const int k = blockIdx.x * blockDim.x + threadIdx.x;   // 4x256 = 1024 threads
    if (k >= KTOT) return;
    int run = 0;
    for (int b = 0; b < NB; ++b) {               // coalesced: consecutive k adjacent
        int t = hist[(size_t)b * KTOT + k];
        hist[(size_t)b * KTOT + k] = run;
        run += t;
    }
    counts[k] = run;
}

// ---------------- K5b: exclusive prefix scan over K=1024 codes ----------------
__global__ void k_scan(const int* __restrict__ counts, int* __restrict__ offsets)
{
    __shared__ int a[KTOT];
    const int tid = threadIdx.x;
    int c = counts[tid];
    a[tid] = c;
    __syncthreads();
    for (int off = 1; off < KTOT; off <<= 1) {
        int v = (tid >= off) ? a[tid - off] : 0;
        __syncthreads();
        a[tid] += v;
        __syncthreads();
    }
    offsets[tid] = a[tid] - c;
}

// ---------------- K6: place via LDS cursors (zero global atomics) ----------------
// R7/R8 lesson: 262k global atomics on skewed codes -> hottest cursor word
// serializes ~7.5k RMWs = 145us. Deterministic bases + LDS-local cursors instead.
__global__ void k_place2(const unsigned int* __restrict__ idx, const int* __restrict__ hist,
                         const int* __restrict__ offsets, unsigned* __restrict__ order, int N)
{
    __shared__ int cur[KTOT];
    const int tid = threadIdx.x;
    const int b = blockIdx.x;
    for (int i = tid; i < KTOT; i += blockDim.x)
        cur[i] = offsets[i] + hist[(size_t)b * KTOT + i];
    __syncthreads();
    const int chunk = N / NB;
    const int p0 = b * chunk;
    for (int i = tid; i < chunk; i += blockDim.x) {
        int p = p0 + i;
        unsigned k = idx[p] & 0x7fffffffu;
        int pos = atomicAdd(&cur[k], 1);         // LDS atomic; worst code ~60 RMWs/block
        order[pos] = (k << 18) | (unsigned)p;
    }
}

// ---------------- K7: balanced run-length segment sum + fused quant gather ----------------
__global__ void k_sum(const float* __restrict__ x, const float* __restrict__ wT,
                      const unsigned* __restrict__ order, float* __restrict__ quant,
                      float* __restrict__ cs, int N)
{
    const int gtid = blockIdx.x * blockDim.x + threadIdx.x;
    const int lane = threadIdx.x & 63;
    const int wave = gtid >> 6;
    const int nwaves = (gridDim.x * blockDim.x) >> 6;
    const int nchunks = (N + 63) >> 6;

    for (int c = wave; c < nchunks; c += nwaves) {
        const int base = c << 6;
        const int cnt = min(64, N - base);
        unsigned e = order[base + min(lane, cnt - 1)];   // coalesced 256B

        int curk = -1;
        float acc = 0.f, wrow = 0.f;
        unsigned e0 = __shfl(e, 0);
        int k0 = (int)(e0 >> 18), p0 = (int)(e0 & PMASK);
        float v = x[(size_t)p0 * D + lane];
        for (int i = 0; i < cnt; ++i) {
            int kn = 0, pn = 0;
            float vn = 0.f;
            if (i + 1 < cnt) {                           // wave-uniform branch
                unsigned en = __shfl(e, i + 1);
                kn = (int)(en >> 18);
                pn = (int)(en & PMASK);
                vn = x[(size_t)pn * D + lane];
            }
            if (k0 != curk) {                            // wave-uniform
                if (curk >= 0) unsafeAtomicAdd(&cs[(size_t)curk * D + lane], acc);
                wrow = wT[(size_t)k0 * D + lane];        // L2-hot
                acc = v;
                curk = k0;
            } else {
                acc += v;
            }
            quant[(size_t)p0 * D + lane] = wrow;
            k0 = kn; p0 = pn; v = vn;
        }
        unsafeAtomicAdd(&cs[(size_t)curk * D + lane], acc);
    }
}

// ---------------- K8: EMA combine -> new_w [D][K] ----------------
__global__ void k_combine(const float* __restrict__ c_sum, const float* __restrict__ c_n,
                          const float* __restrict__ cs, const int* __restrict__ counts,
                          float* __restrict__ outw, int K)
{
    int i = blockIdx.x * blockDim.x + threadIdx.x;   // i = d*K + k
    if (i >= D * K) return;
    int k = i % K;
    int d = i / K;
    const float g  = 0.99f;
    const float og = (float)(1.0 - 0.99);
    float ns = c_sum[i] * g + cs[(size_t)k * D + d] * og;
    float nn = c_n[k] * g + (float)counts[k] * og;
    outw[i] = ns / nn;
}

extern "C" void kernel_launch(void* const* d_in, const int* in_sizes, int n_in,
                              void* d_out, int out_size, void* d_ws, size_t ws_size,
                              hipStream_t stream)
{
    const float* x     = (const float*)d_in[0];
    const float* w     = (const float*)d_in[1];
    const float* c_sum = (const float*)d_in[2];
    const float* c_n   = (const float*)d_in[3];
    const int N = in_sizes[0] / D;
    const int K = in_sizes[3];

    float* quant = (float*)d_out;                      // N*D
    float* outw  = (float*)d_out + (size_t)N * D;      // D*K

    // ws layout: [cs K*D][wl_count 1]  <- one memset covers these
    //            [hist NB*K][counts K][offsets K][wl WLCAP][order N][idx N][wn K][wT K*D][wpacks]
    char* ws = (char*)d_ws;
    float* cs       = (float*)ws;                      // K*D
    int* wl_count   = (int*)(cs + (size_t)K * D);      // 1
    int* hist       = wl_count + 1;                    // NB*K (fully written by k_hist2)
    int* counts     = hist + (size_t)NB * KTOT;        // K (written by k_tot)
    int* offsets    = counts + K;                      // K (written by k_scan)
    int* wl         = offsets + K;                     // WLCAP
    unsigned* order = (unsigned*)(wl + WLCAP);         // N
    unsigned* idx   = order + N;                       // N
    float* wn       = (float*)(idx + N);               // K
    float* wT       = wn + K;                          // K*D
    unsigned short* wpack_hi = (unsigned short*)(wT + (size_t)K * D);
    unsigned short* wpack_lo = wpack_hi + (size_t)K * D;

    hipMemsetAsync(cs, 0, ((size_t)K * D + 1) * sizeof(float), stream);
    k_prep_w<<<(D * K + 255) / 256, 256, 0, stream>>>(w, wpack_hi, wpack_lo, wT, K);
    k_wn<<<(K + 255) / 256, 256, 0, stream>>>(w, wn, K);

    k_assign<<<(N + 127) / 128, 256, 0, stream>>>(x, wpack_hi, wpack_lo, wn, idx, wl, wl_count, N, K);
    k_refine<<<1024, 256, 0, stream>>>(x, w, idx, wl, wl_count, N, K);

    k_hist2<<<NB, 256, 0, stream>>>(idx, hist, N);
    k_tot<<<4, 256, 0, stream>>>(hist, counts);
    k_scan<<<1, KTOT, 0, stream>>>(counts, offsets);
    k_place2<<<NB, 256, 0, stream>>>(idx, hist, offsets, order, N);
    k_sum<<<1024, 256, 0, stream>>>(x, wT, order, quant, cs, N);
    k_combine<<<(D * K + 255) / 256, 256, 0, stream>>>(c_sum, c_n, cs, counts, outw, K);
}

// Round 10
// 298.360 us; speedup vs baseline: 5.9489x; 1.0513x over previous
//
#include <hip/hip_runtime.h>
#include <hip/hip_fp16.h>
#include <cmath>

#define D 64
#define KTOT 1024
#define MARGIN_P 0.03125f  // flag margin: pack-trunc (<=0.0156) + fp16-2term err (sigma~1.6e-3)
#define WLCAP 32768        // refine worklist capacity
#define PMASK 0x3FFFFu     // low 18 bits: point id (N = 2^18)
#define NB 128             // blocks for hist/place counting sort

typedef __attribute__((ext_vector_type(8))) _Float16 half8;  // 8 fp16 = 4 VGPRs (MFMA A/B frag)
typedef __attribute__((ext_vector_type(4))) float f32x4;     // MFMA C/D frag

// ---------------- K0: pack w into MFMA B-frag fp16 + transpose + wn (fused) ----------------
// blocks [0, DK/256): pack; blocks [DK/256, +4): wn[k] = 0.5*||w_k||^2 fp64
__global__ void k_prep(const float* __restrict__ w, unsigned short* __restrict__ wpack_hi,
                       float* __restrict__ wT, float* __restrict__ wn, int K)
{
    const int nprep = (D * K) / 256;
    if ((int)blockIdx.x < nprep) {
        int i = blockIdx.x * 256 + threadIdx.x;  // i = d*K + k
        int d = i / K, k = i % K;
        float f = w[i];
        _Float16 h = (_Float16)f;                // RNE
        int t = k >> 4, n = k & 15;
        int kc = d >> 5, q = (d >> 3) & 3, j = d & 7;
        size_t fi = ((size_t)((t * 2 + kc) * 64 + q * 16 + n)) * 8 + j;
        __half hh = *(__half*)&h;
        wpack_hi[fi] = __half_as_ushort(hh);
        wT[(size_t)k * D + d] = f;
    } else {
        int k = (blockIdx.x - nprep) * 256 + threadIdx.x;
        if (k >= K) return;
        double s = 0.0;
        for (int d = 0; d < D; ++d) {
            double v = (double)w[(size_t)d * K + k];
            s += v * v;
        }
        wn[k] = (float)(0.5 * s);
    }
}

// ---------------- K2: MFMA assign (fp16 2-term), packed-uint argmax + block worklist ----------------
__global__ __launch_bounds__(256, 4) void k_assign(
    const float* __restrict__ x, const unsigned short* __restrict__ wpack_hi,
    const float* __restrict__ wn, unsigned int* __restrict__ idx_out,
    int* __restrict__ wl, int* __restrict__ wl_count, int N, int K)
{
    __shared__ __align__(16) unsigned short lds_hi[8192];  // 16 KB (w in fp16, no lo)
    __shared__ float lds_wn[128];
    __shared__ int l_wl[128];    // 128 = physical max points/block
    __shared__ int l_cnt, l_base;

    const int tid = threadIdx.x;
    const int wv = tid >> 6, lane = tid & 63;
    const int col = lane & 15, quad = lane >> 4;
    const long long n0 = (long long)blockIdx.x * 128 + wv * 32;
    if (tid == 0) l_cnt = 0;

    // A-frags: x split into fp16 hi/lo (x = hi + lo + O(2^-22))
    half8 a_hi[2][2], a_lo[2][2];
    #pragma unroll
    for (int mt = 0; mt < 2; ++mt) {
        long long row = n0 + mt * 16 + col;
        if (row >= N) row = N - 1;
        const float* xr = x + row * D;
        #pragma unroll
        for (int kc = 0; kc < 2; ++kc) {
            const int dbase = kc * 32 + quad * 8;
            float4 f0 = *(const float4*)(xr + dbase);
            float4 f1 = *(const float4*)(xr + dbase + 4);
            float xs[8] = {f0.x, f0.y, f0.z, f0.w, f1.x, f1.y, f1.z, f1.w};
            half8 h, l;
            #pragma unroll
            for (int j = 0; j < 8; ++j) {
                _Float16 hj = (_Float16)xs[j];
                h[j] = hj;
                l[j] = (_Float16)(xs[j] - (float)hj);
            }
            a_hi[mt][kc] = h;
            a_lo[mt][kc] = l;
        }
    }

    // packed (biased-value | 1023-code): max_u32 argmax, min/max top-2
    unsigned best[8], sec[8];
    #pragma unroll
    for (int s = 0; s < 8; ++s) { best[s] = 0u; sec[s] = 0u; }

    const int nchunks = K / 128;
    for (int c = 0; c < nchunks; ++c) {
        __syncthreads();
        {   // stage 16 KB + 512 B wn
            const uint4* gh = (const uint4*)(wpack_hi + (size_t)c * 8192);
            uint4* lh = (uint4*)lds_hi;
            #pragma unroll
            for (int i = 0; i < 4; ++i)
                lh[tid + 256 * i] = gh[tid + 256 * i];
            if (tid < 128) lds_wn[tid] = wn[c * 128 + tid];
        }
        __syncthreads();

        #pragma unroll
        for (int tl = 0; tl < 8; ++tl) {
            const int fb = (tl * 2) * 512 + (quad * 16 + col) * 8;
            half8 bh0 = *(const half8*)(lds_hi + fb);
            half8 bh1 = *(const half8*)(lds_hi + fb + 512);
            const float base = 128.0f - lds_wn[tl * 16 + col];   // bias + (-wn) in acc init
            const unsigned codebits = 1023u - (unsigned)((c * 8 + tl) * 16 + col);
            #pragma unroll
            for (int mt = 0; mt < 2; ++mt) {
                f32x4 acc = {base, base, base, base};
                acc = __builtin_amdgcn_mfma_f32_16x16x32_f16(a_hi[mt][0], bh0, acc, 0, 0, 0);
                acc = __builtin_amdgcn_mfma_f32_16x16x32_f16(a_hi[mt][1], bh1, acc, 0, 0, 0);
                acc = __builtin_amdgcn_mfma_f32_16x16x32_f16(a_lo[mt][0], bh0, acc, 0, 0, 0);
                acc = __builtin_amdgcn_mfma_f32_16x16x32_f16(a_lo[mt][1], bh1, acc, 0, 0, 0);
                #pragma unroll
                for (int r = 0; r < 4; ++r) {
                    unsigned pv = (__float_as_uint(acc[r]) & 0xFFFFFC00u) | codebits;
                    int s = mt * 4 + r;
                    unsigned b = best[s];
                    unsigned mn = pv < b ? pv : b;
                    best[s] = pv > b ? pv : b;
                    sec[s]  = mn > sec[s] ? mn : sec[s];
                }
            }
        }
    }

    // top-2 merge across the 16 columns
    #pragma unroll
    for (int m = 1; m < 16; m <<= 1) {
        #pragma unroll
        for (int s = 0; s < 8; ++s) {
            unsigned ob = __shfl_xor(best[s], m);
            unsigned os = __shfl_xor(sec[s], m);
            unsigned mn = ob < best[s] ? ob : best[s];
            best[s] = ob > best[s] ? ob : best[s];
            sec[s]  = os > sec[s] ? os : sec[s];
            sec[s]  = mn > sec[s] ? mn : sec[s];
        }
    }

    if (col == 0) {
        #pragma unroll
        for (int s = 0; s < 8; ++s) {
            int mt = s >> 2, r = s & 3;
            long long np = n0 + mt * 16 + quad * 4 + r;   // C row = quad*4 + reg
            if (np < N) {
                unsigned code = 1023u - (best[s] & 0x3FFu);
                float vb = __uint_as_float(best[s] & 0xFFFFFC00u);
                float vs = __uint_as_float(sec[s] & 0xFFFFFC00u);
                if ((vb - vs) < MARGIN_P) {
                    idx_out[np] = code | 0x80000000u;
                    int q = atomicAdd(&l_cnt, 1);        // LDS atomic
                    l_wl[q] = (int)np;
                } else {
                    idx_out[np] = code;
                }
            }
        }
    }
    __syncthreads();
    if (tid == 0 && l_cnt > 0) l_base = atomicAdd(wl_count, l_cnt);  // 1 global RMW/block
    __syncthreads();
    for (int i = tid; i < l_cnt; i += 256) {
        int pos = l_base + i;
        if (pos < WLCAP) wl[pos] = l_wl[i];
    }
}

// ---------------- K3: fp64 exact rescan of worklist points ----------------
__global__ void k_refine(const float* __restrict__ x, const float* __restrict__ w,
                         unsigned int* __restrict__ idx_io, const int* __restrict__ wl,
                         const int* __restrict__ wl_count, int N, int K)
{
    const int gtid = blockIdx.x * blockDim.x + threadIdx.x;
    const int lane = threadIdx.x & 63;
    const int wave = gtid >> 6;
    const int nwaves = (gridDim.x * blockDim.x) >> 6;
    int nw = wl_count[0];
    if (nw > WLCAP) nw = WLCAP;

    for (int i = wave; i < nw; i += nwaves) {
        long long p = wl[i];
        const float* __restrict__ xp = x + p * D;   // wave-uniform broadcast, L1-hot
        double bt = -1e300;
        int bk = 0;
        for (int k = lane; k < K; k += 64) {        // ascending k/lane; strict > = first-occurrence
            double t = 0.0, s = 0.0;
            #pragma unroll 8
            for (int d = 0; d < D; ++d) {
                double wd = (double)w[(size_t)d * K + k];
                t = fma((double)xp[d], wd, t);
                s = fma(wd, wd, s);
            }
            t -= 0.5 * s;
            if (t > bt) { bt = t; bk = k; }
        }
        #pragma unroll
        for (int off = 32; off > 0; off >>= 1) {
            double ot = __shfl_down(bt, off);
            int    ok = __shfl_down(bk, off);
            if (ot > bt || (ot == bt && ok < bk)) { bt = ot; bk = ok; }
        }
        int fk = __shfl(bk, 0);
        if (lane == 0) idx_io[p] = (unsigned)fk;    // clear flag
    }
}

// ---------------- K4: per-block histogram, plain writes (no global atomics) ----------------
__global__ void k_hist2(const unsigned int* __restrict__ idx, int* __restrict__ hist, int N)
{
    __shared__ int h[KTOT];
    const int tid = threadIdx.x;
    const int b = blockIdx.x;
    for (int i = tid; i < KTOT; i += blockDim.x) h[i] = 0;
    __syncthreads();
    const int chunk = N / NB;
    const int p0 = b * chunk;
    for (int i = tid; i < chunk; i += blockDim.x)
        atomicAdd(&h[idx[p0 + i] & 0x7fffffffu], 1);
    __syncthreads();
    for (int i = tid; i < KTOT; i += blockDim.x)
        hist[(size_t)b * KTOT + i] = h[i];
}

// ---------------- K5: fused per-code block-scan + code prefix-scan (1 block, 1024 thr) ----------------
__global__ void k_totscan(int* __restrict__ hist, int* __restrict__ counts,
                          int* __restrict__ offsets)
{
    __shared__ int a[KTOT];
    const int k = threadIdx.x;
    int run = 0;
    #pragma unroll 8
    for (int b = 0; b < NB; ++b) {               // coalesced across k
        int t = hist[(size_t)b * KTOT + k];
        hist[(size_t)b * KTOT + k] = run;
        run += t;
    }
    counts[k] = run;
    a[k] = run;
    __syncthreads();
    for (int off = 1; off < KTOT; off <<= 1) {
        int v = (k >= off) ? a[k - off] : 0;
        __syncthreads();
        a[k] += v;
        __syncthreads();
    }
    offsets[k] = a[k] - run;
}

// ---------------- K6: place via LDS cursors (zero global atomics) ----------------
__global__ void k_place2(const unsigned int* __restrict__ idx, const int* __restrict__ hist,
                         const int* __restrict__ offsets, unsigned* __restrict__ order, int N)
{
    __shared__ int cur[KTOT];
    const int tid = threadIdx.x;
    const int b = blockIdx.x;
    for (int i = tid; i < KTOT; i += blockDim.x)
        cur[i] = offsets[i] + hist[(size_t)b * KTOT + i];
    __syncthreads();
    const int chunk = N / NB;
    const int p0 = b * chunk;
    for (int i = tid; i < chunk; i += blockDim.x) {
        int p = p0 + i;
        unsigned k = idx[p] & 0x7fffffffu;
        int pos = atomicAdd(&cur[k], 1);         // LDS atomic; worst code ~60 RMWs/block
        order[pos] = (k << 18) | (unsigned)p;
    }
}

// ---------------- K7: balanced run-length segment sum + fused quant gather ----------------
__global__ void k_sum(const float* __restrict__ x, const float* __restrict__ wT,
                      const unsigned* __restrict__ order, float* __restrict__ quant,
                      float* __restrict__ cs, int N)
{
    const int gtid = blockIdx.x * blockDim.x + threadIdx.x;
    const int lane = threadIdx.x & 63;
    const int wave = gtid >> 6;
    const int nwaves = (gridDim.x * blockDim.x) >> 6;
    const int nchunks = (N + 63) >> 6;

    for (int c = wave; c < nchunks; c += nwaves) {
        const int base = c << 6;
        const int cnt = min(64, N - base);
        unsigned e = order[base + min(lane, cnt - 1)];   // coalesced 256B

        int curk = -1;
        float acc = 0.f, wrow = 0.f;
        unsigned e0 = __shfl(e, 0);
        int k0 = (int)(e0 >> 18), p0 = (int)(e0 & PMASK);
        float v = x[(size_t)p0 * D + lane];
        for (int i = 0; i < cnt; ++i) {
            int kn = 0, pn = 0;
            float vn = 0.f;
            if (i + 1 < cnt) {                           // wave-uniform branch
                unsigned en = __shfl(e, i + 1);
                kn = (int)(en >> 18);
                pn = (int)(en & PMASK);
                vn = x[(size_t)pn * D + lane];
            }
            if (k0 != curk) {                            // wave-uniform
                if (curk >= 0) unsafeAtomicAdd(&cs[(size_t)curk * D + lane], acc);
                wrow = wT[(size_t)k0 * D + lane];        // L2-hot
                acc = v;
                curk = k0;
            } else {
                acc += v;
            }
            quant[(size_t)p0 * D + lane] = wrow;
            k0 = kn; p0 = pn; v = vn;
        }
        unsafeAtomicAdd(&cs[(size_t)curk * D + lane], acc);
    }
}

// ---------------- K8: EMA combine -> new_w [D][K] ----------------
__global__ void k_combine(const float* __restrict__ c_sum, const float* __restrict__ c_n,
                          const float* __restrict__ cs, const int* __restrict__ counts,
                          float* __restrict__ outw, int K)
{
    int i = blockIdx.x * blockDim.x + threadIdx.x;   // i = d*K + k
    if (i >= D * K) return;
    int k = i % K;
    int d = i / K;
    const float g  = 0.99f;
    const float og = (float)(1.0 - 0.99);
    float ns = c_sum[i] * g + cs[(size_t)k * D + d] * og;
    float nn = c_n[k] * g + (float)counts[k] * og;
    outw[i] = ns / nn;
}

extern "C" void kernel_launch(void* const* d_in, const int* in_sizes, int n_in,
                              void* d_out, int out_size, void* d_ws, size_t ws_size,
                              hipStream_t stream)
{
    const float* x     = (const float*)d_in[0];
    const float* w     = (const float*)d_in[1];
    const float* c_sum = (const float*)d_in[2];
    const float* c_n   = (const float*)d_in[3];
    const int N = in_sizes[0] / D;
    const int K = in_sizes[3];

    float* quant = (float*)d_out;                      // N*D
    float* outw  = (float*)d_out + (size_t)N * D;      // D*K

    // ws layout: [cs K*D][wl_count 1] <- one memset | [hist NB*K][counts K][offsets K]
    //            [wl WLCAP][order N][idx N][wn K][wT K*D][wpack_hi K*D ushort]
    char* ws = (char*)d_ws;
    float* cs       = (float*)ws;                      // K*D
    int* wl_count   = (int*)(cs + (size_t)K * D);      // 1
    int* hist       = wl_count + 1;                    // NB*K
    int* counts     = hist + (size_t)NB * KTOT;        // K
    int* offsets    = counts + K;                      // K
    int* wl         = offsets + K;                     // WLCAP
    unsigned* order = (unsigned*)(wl + WLCAP);         // N
    unsigned* idx   = order + N;                       // N
    float* wn       = (float*)(idx + N);               // K
    float* wT       = wn + K;                          // K*D
    unsigned short* wpack_hi = (unsigned short*)(wT + (size_t)K * D);

    hipMemsetAsync(cs, 0, ((size_t)K * D + 1) * sizeof(float), stream);
    k_prep<<<(D * K) / 256 + 4, 256, 0, stream>>>(w, wpack_hi, wT, wn, K);

    k_assign<<<(N + 127) / 128, 256, 0, stream>>>(x, wpack_hi, wn, idx, wl, wl_count, N, K);
    k_refine<<<1024, 256, 0, stream>>>(x, w, idx, wl, wl_count, N, K);

    k_hist2<<<NB, 256, 0, stream>>>(idx, hist, N);
    k_totscan<<<1, KTOT, 0, stream>>>(hist, counts, offsets);
    k_place2<<<NB, 256, 0, stream>>>(idx, hist, offsets, order, N);
    k_sum<<<1024, 256, 0, stream>>>(x, wT, order, quant, cs, N);
    k_combine<<<(D * K + 255) / 256, 256, 0, stream>>>(c_sum, c_n, cs, counts, outw, K);
}